// Round 6
// baseline (434.666 us; speedup 1.0000x reference)
//
#include <hip/hip_runtime.h>

typedef unsigned short u16;
typedef __bf16 bf16x8 __attribute__((ext_vector_type(8)));
typedef float f32x4 __attribute__((ext_vector_type(4)));

// ---------- sizes ----------
#define Bsz 8192
#define Fdim 1024
#define Udim 512
#define Odim 3
#define Adim 6
#define Hdim 4

// ws element offsets (u16 elements)
#define OFF_FEAT   0
#define OFF_WAL    8388608     // W_lat = [W_al ; W_ol] contiguous (2048 x 1024)
#define OFF_WOL    8912896
#define OFF_WIN    10485760
#define OFF_WOUT   11272192
#define OFF_WAH    11534336
#define OFF_WOH    12058624
#define OFF_LAT    12845056    // B x 2048 : [agent_latent | opp0 | opp1 | opp2]

// d_out offsets (fp32 elements)
#define OUT_AP 0
#define OUT_AV 49152
#define OUT_OP 57344
#define OUT_OV 204800
#define OUT_IN 229376

__device__ __forceinline__ u16 f2bf(float f) {
  return __builtin_bit_cast(u16, (__bf16)f);
}
__device__ __forceinline__ float bf2f(u16 u) {
  return (float)__builtin_bit_cast(__bf16, u);
}

__device__ __forceinline__ void gload16(const u16* g, u16* s) {
  __builtin_amdgcn_global_load_lds(
      (const __attribute__((address_space(1))) unsigned int*)g,
      (__attribute__((address_space(3))) unsigned int*)s, 16, 0, 0);
}

// ---------- fp32 -> bf16 conversion of features + all GEMM weights ----------
#define CV_E0 2097152
#define CV_E1 2228224
#define CV_E2 2621440
#define CV_E3 2818048
#define CV_E4 2883584
#define CV_E5 3014656
#define CV_E6 3211264
__global__ __launch_bounds__(256) void convert_all(
    const float* __restrict__ f, const float* __restrict__ wal,
    const float* __restrict__ wol, const float* __restrict__ win,
    const float* __restrict__ wout, const float* __restrict__ wah,
    const float* __restrict__ woh, u16* __restrict__ dst) {
  int i = blockIdx.x * 256 + threadIdx.x;
  if (i >= CV_E6) return;
  const float* src;
  int base;
  if (i < CV_E0)      { src = f;    base = 0; }
  else if (i < CV_E1) { src = wal;  base = CV_E0; }
  else if (i < CV_E2) { src = wol;  base = CV_E1; }
  else if (i < CV_E3) { src = win;  base = CV_E2; }
  else if (i < CV_E4) { src = wout; base = CV_E3; }
  else if (i < CV_E5) { src = wah;  base = CV_E4; }
  else                { src = woh;  base = CV_E5; }
  float4 v = ((const float4*)src)[i - base];
  ushort4 o;
  o.x = f2bf(v.x); o.y = f2bf(v.y); o.z = f2bf(v.z); o.w = f2bf(v.w);
  ((ushort4*)dst)[i] = o;
}

// ============================================================================
// 256x256 8-phase bf16 GEMM for lat = elu(feat @ W_lat^T + b). Unchanged from
// round 2 (verified: FETCH near-ideal, 0 bank conflicts).
// ============================================================================
#define BAR() __builtin_amdgcn_s_barrier()
#define FENCE() asm volatile("" ::: "memory")
#define LGKM0() asm volatile("s_waitcnt lgkmcnt(0)" ::: "memory")
#define VMW(n) asm volatile("s_waitcnt vmcnt(" #n ")" ::: "memory")
#define MFMA(a, b, c) __builtin_amdgcn_mfma_f32_16x16x32_bf16(a, b, c, 0, 0, 0)
#define STAGE(MAT, SRC, LD, buf, ks, kb) do {                    \
    const u16* _s = (SRC) + (size_t)(kb) + (ks) * 32;            \
    gload16(_s, &MAT[buf][ks][wave * 512]);                      \
    gload16(_s + (size_t)128 * (LD), &MAT[buf][ks][4096 + wave * 512]); \
  } while (0)
#define RD_A(cur, ks, mh) do {                                   \
    _Pragma("unroll")                                            \
    for (int mi = 0; mi < 4; mi++)                               \
      a0[mi] = *(const bf16x8*)&As[cur][ks][aoff + (mh)*2048 + mi*512]; \
  } while (0)
#define RD_B(cur, ks) do {                                       \
    _Pragma("unroll")                                            \
    for (int ni = 0; ni < 4; ni++)                               \
      b0[ni] = *(const bf16x8*)&Bs[cur][ks][boff + ni*512];      \
  } while (0)
#define MFMA8(mh) do {                                           \
    __builtin_amdgcn_s_setprio(1);                               \
    _Pragma("unroll")                                            \
    for (int mi = 0; mi < 4; mi++) {                             \
      _Pragma("unroll")                                          \
      for (int ni = 0; ni < 4; ni++)                             \
        acc[(mh)*4+mi][ni] = MFMA(a0[mi], b0[ni], acc[(mh)*4+mi][ni]); \
    }                                                            \
    __builtin_amdgcn_s_setprio(0);                               \
  } while (0)

template <bool ELU>
__global__ __launch_bounds__(512, 2) void gemm256(
    const u16* __restrict__ A, const u16* __restrict__ Bw, u16* __restrict__ C,
    const float* __restrict__ bias1, const float* __restrict__ bias2,
    int bsplit, int K, int lda, int ldb, int ldc,
    long sAz, long sBz, long sCz, int sbz, float scale) {
  __shared__ __align__(16) u16 As[2][2][8192];
  __shared__ __align__(16) u16 Bs[2][2][8192];
  const int tid = threadIdx.x;
  const int wave = tid >> 6, lane = tid & 63;
  const int wr = wave >> 2, wc = wave & 3;

  const int nx = gridDim.x, ny = gridDim.y;
  const int nxy = nx * ny;
  const int nwg = nxy * gridDim.z;
  const int orig = blockIdx.x + nx * (blockIdx.y + ny * blockIdx.z);
  const int xcd = orig & 7;
  const int qd = nwg >> 3, rd = nwg & 7;
  const int wg = (xcd < rd ? xcd * (qd + 1) : rd * (qd + 1) + (xcd - rd) * qd)
               + (orig >> 3);
  const int z = wg / nxy;
  const int rem = wg - z * nxy;
  const int by = rem / nx;
  const int bx = rem - by * nx;

  A += (size_t)z * sAz;
  Bw += (size_t)z * sBz;
  C += (size_t)z * sCz;
  bias1 += (size_t)z * sbz;

  const int tM = by * 256, tN = bx * 256;

  const int srow = tid >> 2;
  const int schunk = ((tid & 3) ^ ((tid >> 3) & 3)) * 8;
  const u16* Asrc = A + (size_t)(tM + srow) * lda + schunk;
  const u16* Bsrc = Bw + (size_t)(tN + srow) * ldb + schunk;

  const int laneLo = lane & 15;
  const int pc8 = (((lane >> 4) ^ ((lane >> 1) & 3))) * 8;
  const int aoff = (wr * 128 + laneLo) * 32 + pc8;
  const int boff = (wc * 64 + laneLo) * 32 + pc8;

  f32x4 acc[8][4];
#pragma unroll
  for (int mi = 0; mi < 8; mi++)
#pragma unroll
    for (int ni = 0; ni < 4; ni++) acc[mi][ni] = (f32x4){0.f, 0.f, 0.f, 0.f};

  const int NT = K >> 6;

  STAGE(As, Asrc, lda, 0, 0, 0);
  STAGE(Bs, Bsrc, ldb, 0, 0, 0);
  STAGE(As, Asrc, lda, 0, 1, 0);
  STAGE(Bs, Bsrc, ldb, 0, 1, 0);
  VMW(4);
  BAR();

  int cur = 0;
  int kb = 64;
  bf16x8 a0[4], b0[4];
  for (int t = 0; t < NT; ++t) {
    const int nxt = cur ^ 1;
    const bool st = (t + 1 < NT);
    RD_B(cur, 0);
    RD_A(cur, 0, 0);
    if (st) STAGE(As, Asrc, lda, nxt, 0, kb);
    FENCE(); BAR(); LGKM0();
    MFMA8(0);
    FENCE(); BAR();
    RD_A(cur, 0, 1);
    if (st) STAGE(Bs, Bsrc, ldb, nxt, 0, kb);
    FENCE(); BAR(); LGKM0();
    MFMA8(1);
    if (st) { VMW(4); } else { VMW(0); }
    BAR();
    RD_B(cur, 1);
    RD_A(cur, 1, 0);
    if (st) STAGE(As, Asrc, lda, nxt, 1, kb);
    FENCE(); BAR(); LGKM0();
    MFMA8(0);
    FENCE(); BAR();
    RD_A(cur, 1, 1);
    if (st) STAGE(Bs, Bsrc, ldb, nxt, 1, kb);
    FENCE(); BAR(); LGKM0();
    MFMA8(1);
    if (st) { VMW(4); BAR(); }
    cur = nxt;
    kb += 64;
  }

#pragma unroll
  for (int ni = 0; ni < 4; ni++) {
    const int col = tN + wc * 64 + ni * 16 + laneLo;
    const float bv = (col < bsplit) ? bias1[col] : bias2[col - bsplit];
#pragma unroll
    for (int gm = 0; gm < 8; gm++) {
      const int row0 = tM + wr * 128 + gm * 16 + (lane >> 4) * 4;
#pragma unroll
      for (int r = 0; r < 4; r++) {
        float v = (acc[gm][ni][r] + bv) * scale;
        if (ELU) v = v > 0.f ? v : (__expf(v) - 1.f);
        C[(size_t)(row0 + r) * ldc + col] = f2bf(v);
      }
    }
  }
}
#undef STAGE
#undef RD_A
#undef RD_B
#undef MFMA8

// ============================================================================
// brain v2: same fused dataflow as round 4/5 (math + layouts harness-verified)
// but weight B-operands are now STAGED into LDS per 32-K chunk via
// global_load_lds (fire-and-forget; __syncthreads drains vmcnt) instead of
// register-streamed dependent global loads (r5: 660 cyc/load exposed latency,
// MfmaUtil 9.9%). Latents: AL + single restaged OLX + scratch S2.
// agh/oph outputs stored XOR-swizzled so DOTS reads are conflict-free.
// LDS = 4 x 32KB + sc/wt = 135680 B (same allocation as r5, known-good).
// ============================================================================

#define ZACC2(ACC) do {                                                        \
    _Pragma("unroll")                                                          \
    for (int mf_ = 0; mf_ < 2; ++mf_)                                          \
      _Pragma("unroll")                                                        \
      for (int nf_ = 0; nf_ < 4; ++nf_)                                        \
        ACC[mf_][nf_] = (f32x4){0.f, 0.f, 0.f, 0.f};                           \
  } while (0)

// restage one 32x512 latent slice (columns CB..CB+511 of lat) into OLX,
// chunk-XOR swizzled exactly like the verified r5 staging.
#define STAGE_LAT(CB) do {                                                     \
    _Pragma("unroll")                                                          \
    for (int j9 = 0; j9 < 4; ++j9) {                                           \
      int gq9 = j9*512 + tid;                                                  \
      int r9 = gq9 >> 6, s9 = gq9 & 63, c9x = s9 ^ (r9 & 7);                   \
      gload16(lat + (size_t)(row0 + r9)*2048 + (CB) + c9x*8,                   \
              &OLX[(size_t)j9*4096 + wave*512]);                               \
    }                                                                          \
  } while (0)

// one K=32 chunk: A-frags from ABUF (512-wide swizzled rows), B-frags from WS.
#define CHUNK(ACC, ABUF, C) do {                                               \
    bf16x8 a0_ = *(const bf16x8*)&(ABUF)[ll*512 + ((((C)*4+lh)^l7)*8)];        \
    bf16x8 a1_ = *(const bf16x8*)&(ABUF)[(16+ll)*512 + ((((C)*4+lh)^l7)*8)];   \
    _Pragma("unroll")                                                          \
    for (int nf_ = 0; nf_ < 4; ++nf_) {                                        \
      bf16x8 bf_ = *(const bf16x8*)&WS[(wc0 + nf_*16 + ll)*32 + wpc8];         \
      ACC[0][nf_] = MFMA(a0_, bf_, ACC[0][nf_]);                               \
      ACC[1][nf_] = MFMA(a1_, bf_, ACC[1][nf_]);                               \
    }                                                                          \
  } while (0)

// 16-chunk section (K=512), single WS buffer: stage -> sync -> compute -> sync
#define WSEC(ACC, WP, LDW, ABUF) do {                                          \
    for (int c9 = 0; c9 < 16; ++c9) {                                          \
      wstage((WP), (LDW), c9*32, WS, tid, wave);                               \
      __syncthreads();                                                         \
      CHUNK(ACC, ABUF, c9);                                                    \
      __syncthreads();                                                         \
    }                                                                          \
  } while (0)

// 28 length-512 dots; BUF rows are XOR-swizzled (chunk ^ (row&7)).
#define DOTS(BUF, WPp, BPp, WVp, BVp, AGENT, OO) do {                          \
    if (wave < 4) {                                                            \
      const int rl_ = wave*8 + (lane >> 3), kq_ = lane & 7;                    \
      const int b_ = row0 + rl_;                                               \
      bf16x8 av_[8];                                                           \
      _Pragma("unroll")                                                        \
      for (int c_ = 0; c_ < 8; ++c_)                                           \
        av_[c_] = *(const bf16x8*)&(BUF)[rl_*512 + (((c_*8 + kq_) ^ (rl_ & 7))*8)]; \
      _Pragma("unroll")                                                        \
      for (int p_ = 0; p_ < 7; ++p_) {                                         \
        const float* wg_ = (p_ < 6) ? (WPp) + p_*512 : (WVp);                  \
        float ac_ = 0.f;                                                       \
        _Pragma("unroll")                                                      \
        for (int c_ = 0; c_ < 8; ++c_) {                                       \
          float4 w0_ = *(const float4*)(wg_ + c_*64 + kq_*8);                  \
          float4 w1_ = *(const float4*)(wg_ + c_*64 + kq_*8 + 4);              \
          ac_ += (float)av_[c_][0]*w0_.x + (float)av_[c_][1]*w0_.y             \
               + (float)av_[c_][2]*w0_.z + (float)av_[c_][3]*w0_.w             \
               + (float)av_[c_][4]*w1_.x + (float)av_[c_][5]*w1_.y             \
               + (float)av_[c_][6]*w1_.z + (float)av_[c_][7]*w1_.w;            \
        }                                                                      \
        ac_ += __shfl_xor(ac_, 1, 64);                                         \
        ac_ += __shfl_xor(ac_, 2, 64);                                         \
        ac_ += __shfl_xor(ac_, 4, 64);                                         \
        if (kq_ == p_) {                                                       \
          if (AGENT) {                                                         \
            if (p_ < 6) out[OUT_AP + b_*6 + p_] = ac_ + (BPp)[p_];             \
            else        out[OUT_AV + b_] = ac_ + (BVp)[0];                     \
          } else {                                                             \
            if (p_ < 6) out[OUT_OP + b_*18 + (OO)*6 + p_] = ac_ + (BPp)[(OO)*6 + p_]; \
            else        out[OUT_OV + b_*3 + (OO)] = ac_ + (BVp)[(OO)];         \
          }                                                                    \
        }                                                                      \
      }                                                                        \
    }                                                                          \
  } while (0)

// stage a 512(N) x 32(K) bf16 weight tile into ws, chunk-XOR swizzled with
// key (row>>1)&3 (the r2-verified gemm256 Bs scheme, measured 0 conflicts).
__device__ __forceinline__ void wstage(const u16* __restrict__ w, int ldbw,
                                       int kofs, u16* ws, int tid, int wave) {
#pragma unroll
  for (int j = 0; j < 4; ++j) {
    int e = j*512 + tid;
    int r = e >> 2, s = e & 3;
    gload16(w + (size_t)r*ldbw + kofs + ((s ^ ((r>>1)&3)) * 8),
            ws + (size_t)(j*512 + wave*64)*8);
  }
}

__global__ __launch_bounds__(512) void brain(
    const u16* __restrict__ lat, const u16* __restrict__ win,
    const u16* __restrict__ wout, const u16* __restrict__ wah,
    const u16* __restrict__ woh,
    const float* __restrict__ b_in, const float* __restrict__ b_out,
    const float* __restrict__ b_ah, const float* __restrict__ b_oh,
    const float* __restrict__ Wap, const float* __restrict__ bap,
    const float* __restrict__ Wav, const float* __restrict__ bav,
    const float* __restrict__ Wop, const float* __restrict__ bop,
    const float* __restrict__ Wov, const float* __restrict__ bov,
    float* __restrict__ out) {
  __shared__ __align__(16) u16 AL[16384];   // agent latent (persistent)
  __shared__ __align__(16) u16 OLX[16384];  // restaged: ol_o / att / agh
  __shared__ __align__(16) u16 S2[16384];   // scratch: aout / oph
  __shared__ __align__(16) u16 WS[16384];   // staged weight chunk 512x32
  __shared__ float sc_s[2][384];
  __shared__ float wt_s[384];

  const int tid = threadIdx.x;
  const int wave = tid >> 6, lane = tid & 63;
  const int ll = lane & 15, lh = lane >> 4, l7 = lane & 7;
  const int wc0 = wave * 64;
  const int wpc8 = (lh ^ ((ll >> 1) & 3)) * 8;   // WS B-frag swizzle
  const int h3 = (wave >> 1) * 3;
  const int wp = wave & 1;
  const int row0 = blockIdx.x * 32;

  // ---- initial stage: AL + OLX(ol_0), zero score buffer ----
#pragma unroll
  for (int j = 0; j < 4; ++j) {
    int gq = j*512 + tid;
    int r = gq >> 6, s = gq & 63, c = s ^ (r & 7);
    const u16* src = lat + (size_t)(row0 + r) * 2048 + c * 8;
    gload16(src,       &AL[(size_t)j*4096 + wave*512]);
    gload16(src + 512, &OLX[(size_t)j*4096 + wave*512]);
  }
  for (int i = tid; i < 768; i += 512) ((float*)sc_s)[i] = 0.f;

  // ---- q = (al @ Wq^T + bq) * scale : registers ----
  f32x4 qacc[2][4];
  ZACC2(qacc);
  WSEC(qacc, win, 512, AL);
#pragma unroll
  for (int nf = 0; nf < 4; ++nf) {
    float bq_ = b_in[wc0 + nf*16 + ll];
#pragma unroll
    for (int mf = 0; mf < 2; ++mf)
#pragma unroll
      for (int rr = 0; rr < 4; ++rr)
        qacc[mf][nf][rr] = (qacc[mf][nf][rr] + bq_) * 0.08838834764831845f;
  }

  // ---- scores: k_o = ol_o @ Wk^T (+bk), dot with q in-register ----
  float bkv[4];
#pragma unroll
  for (int nf = 0; nf < 4; ++nf) bkv[nf] = b_in[512 + wc0 + nf*16 + ll];
  for (int o = 0; o < 3; ++o) {
    if (o > 0) STAGE_LAT(512 * (1 + o));
    f32x4 kacc[2][4];
    ZACC2(kacc);
    WSEC(kacc, win + 262144, 512, OLX);
    float part0[4] = {0.f, 0.f, 0.f, 0.f}, part1[4] = {0.f, 0.f, 0.f, 0.f};
#pragma unroll
    for (int nf = 0; nf < 4; ++nf)
#pragma unroll
      for (int rr = 0; rr < 4; ++rr) {
        part0[rr] += qacc[0][nf][rr] * (kacc[0][nf][rr] + bkv[nf]);
        part1[rr] += qacc[1][nf][rr] * (kacc[1][nf][rr] + bkv[nf]);
      }
#pragma unroll
    for (int rr = 0; rr < 4; ++rr) {
      float p0 = part0[rr], p1 = part1[rr];
      p0 += __shfl_xor(p0, 1, 64); p1 += __shfl_xor(p1, 1, 64);
      p0 += __shfl_xor(p0, 2, 64); p1 += __shfl_xor(p1, 2, 64);
      p0 += __shfl_xor(p0, 4, 64); p1 += __shfl_xor(p1, 4, 64);
      p0 += __shfl_xor(p0, 8, 64); p1 += __shfl_xor(p1, 8, 64);
      if (ll == 0) {
        sc_s[wp][(lh*4 + rr)*12 + h3 + o] = p0;
        sc_s[wp][(16 + lh*4 + rr)*12 + h3 + o] = p1;
      }
    }
  }
  __syncthreads();

  // ---- softmax over O=3 per (row, head) ----
  if (tid < 128) {
    int r = tid >> 2, h = tid & 3;
    int i = r*12 + h*3;
    float s0 = sc_s[0][i+0] + sc_s[1][i+0];
    float s1 = sc_s[0][i+1] + sc_s[1][i+1];
    float s2 = sc_s[0][i+2] + sc_s[1][i+2];
    float m = fmaxf(s0, fmaxf(s1, s2));
    float e0 = __expf(s0 - m), e1 = __expf(s1 - m), e2 = __expf(s2 - m);
    float inv = 1.f / (e0 + e1 + e2);
    wt_s[i+0] = e0 * inv; wt_s[i+1] = e1 * inv; wt_s[i+2] = e2 * inv;
  }
  __syncthreads();

  // ---- influences ----
  if (tid < 96) {
    int r = tid / 3, o = tid - r * 3;
    out[OUT_IN + (size_t)(row0 + r)*3 + o] =
        (wt_s[r*12 + o] + wt_s[r*12 + 3 + o] + wt_s[r*12 + 6 + o] +
         wt_s[r*12 + 9 + o]) * 0.25f;
  }

  // ---- att = sum_o w[row,h,o] * (ol_o @ Wv^T + bv) ----
  float bvv[4];
#pragma unroll
  for (int nf = 0; nf < 4; ++nf) bvv[nf] = b_in[1024 + wc0 + nf*16 + ll];
  f32x4 att[2][4];
  ZACC2(att);
  for (int o = 0; o < 3; ++o) {
    STAGE_LAT(512 * (1 + o));
    f32x4 vacc[2][4];
    ZACC2(vacc);
    WSEC(vacc, win + 524288, 512, OLX);
#pragma unroll
    for (int mf = 0; mf < 2; ++mf)
#pragma unroll
      for (int rr = 0; rr < 4; ++rr) {
        float wv = wt_s[(mf*16 + lh*4 + rr)*12 + h3 + o];
#pragma unroll
        for (int nf = 0; nf < 4; ++nf)
          att[mf][nf][rr] += wv * (vacc[mf][nf][rr] + bvv[nf]);
      }
  }
  // store att (bf16, swizzled) -> OLX (ol_2 dead after last v-section)
#pragma unroll
  for (int mf = 0; mf < 2; ++mf)
#pragma unroll
    for (int nf = 0; nf < 4; ++nf)
#pragma unroll
      for (int rr = 0; rr < 4; ++rr) {
        int row = mf*16 + lh*4 + rr;
        int col = wc0 + nf*16 + ll;
        OLX[row*512 + (((col >> 3) ^ (row & 7))*8) + (col & 7)] =
            f2bf(att[mf][nf][rr]);
      }
  __syncthreads();

  // ---- aout = att @ Wout^T + b_out -> S2 (swizzled) ----
  {
    f32x4 ao[2][4];
    ZACC2(ao);
    WSEC(ao, wout, 512, OLX);
#pragma unroll
    for (int nf = 0; nf < 4; ++nf) {
      float bb = b_out[wc0 + nf*16 + ll];
#pragma unroll
      for (int mf = 0; mf < 2; ++mf)
#pragma unroll
        for (int rr = 0; rr < 4; ++rr) {
          int row = mf*16 + lh*4 + rr;
          int col = wc0 + nf*16 + ll;
          S2[row*512 + (((col >> 3) ^ (row & 7))*8) + (col & 7)] =
              f2bf(ao[mf][nf][rr] + bb);
        }
    }
  }
  __syncthreads();

  // ---- agh = elu([al | aout] @ Wah^T + b_ah) -> OLX (swizzled) ----
  {
    f32x4 gh[2][4];
    ZACC2(gh);
    for (int c = 0; c < 32; ++c) {
      wstage(wah, 1024, c*32, WS, tid, wave);
      __syncthreads();
      if (c < 16) CHUNK(gh, AL, c);
      else        CHUNK(gh, S2, c - 16);
      __syncthreads();
    }
#pragma unroll
    for (int nf = 0; nf < 4; ++nf) {
      float bb = b_ah[wc0 + nf*16 + ll];
#pragma unroll
      for (int mf = 0; mf < 2; ++mf)
#pragma unroll
        for (int rr = 0; rr < 4; ++rr) {
          int row = mf*16 + lh*4 + rr;
          int col = wc0 + nf*16 + ll;
          float v = gh[mf][nf][rr] + bb;
          v = v > 0.f ? v : (__expf(v) - 1.f);
          OLX[row*512 + (((col >> 3) ^ (row & 7))*8) + (col & 7)] = f2bf(v);
        }
    }
  }
  __syncthreads();

  // ---- agent policy/value heads ----
  DOTS(OLX, Wap, bap, Wav, bav, 1, 0);
  __syncthreads();   // protect OLX before restaging

  // ---- opp heads: oph_o = elu(ol_o @ Woh_o^T + b_oh_o) -> S2, then dots ----
  for (int o = 0; o < 3; ++o) {
    STAGE_LAT(512 * (1 + o));
    f32x4 oh[2][4];
    ZACC2(oh);
    WSEC(oh, woh + (size_t)o * 262144, 512, OLX);
#pragma unroll
    for (int nf = 0; nf < 4; ++nf) {
      float bb = b_oh[o*512 + wc0 + nf*16 + ll];
#pragma unroll
      for (int mf = 0; mf < 2; ++mf)
#pragma unroll
        for (int rr = 0; rr < 4; ++rr) {
          int row = mf*16 + lh*4 + rr;
          int col = wc0 + nf*16 + ll;
          float v = oh[mf][nf][rr] + bb;
          v = v > 0.f ? v : (__expf(v) - 1.f);
          S2[row*512 + (((col >> 3) ^ (row & 7))*8) + (col & 7)] = f2bf(v);
        }
    }
    __syncthreads();
    DOTS(S2, Wop + (size_t)o * 3072, bop, Wov + (size_t)o * 512, bov, 0, o);
    __syncthreads();
  }
}

extern "C" void kernel_launch(void* const* d_in, const int* in_sizes, int n_in,
                              void* d_out, int out_size, void* d_ws, size_t ws_size,
                              hipStream_t stream) {
  (void)in_sizes; (void)n_in; (void)out_size; (void)ws_size;
  const float* f     = (const float*)d_in[0];
  const float* W_al  = (const float*)d_in[1];
  const float* b_al  = (const float*)d_in[2];
  const float* W_in  = (const float*)d_in[3];
  const float* b_in  = (const float*)d_in[4];
  const float* W_out = (const float*)d_in[5];
  const float* b_out = (const float*)d_in[6];
  const float* W_ah  = (const float*)d_in[7];
  const float* b_ah  = (const float*)d_in[8];
  const float* W_ap  = (const float*)d_in[9];
  const float* b_ap  = (const float*)d_in[10];
  const float* W_av  = (const float*)d_in[11];
  const float* b_av  = (const float*)d_in[12];
  const float* W_ol  = (const float*)d_in[13];
  const float* b_ol  = (const float*)d_in[14];
  const float* W_oh  = (const float*)d_in[15];
  const float* b_oh  = (const float*)d_in[16];
  const float* W_op  = (const float*)d_in[17];
  const float* b_op  = (const float*)d_in[18];
  const float* W_ov  = (const float*)d_in[19];
  const float* b_ov  = (const float*)d_in[20];
  float* out = (float*)d_out;
  u16* ws = (u16*)d_ws;

  u16* feat = ws + OFF_FEAT;
  u16* wal  = ws + OFF_WAL;   // [W_al ; W_ol] = W_lat (2048 x 1024)
  u16* win  = ws + OFF_WIN;
  u16* wout = ws + OFF_WOUT;
  u16* wah  = ws + OFF_WAH;
  u16* woh  = ws + OFF_WOH;
  u16* lat  = ws + OFF_LAT;   // B x 2048

  convert_all<<<12544, 256, 0, stream>>>(f, W_al, W_ol, W_in, W_out, W_ah,
                                         W_oh, ws);

  // lat = elu(feat @ W_lat^T + [b_al|b_ol]) : B x 2048
  gemm256<true><<<dim3(8, 32, 1), 512, 0, stream>>>(
      feat, wal, lat, b_al, b_ol, 512, 1024, 1024, 1024, 2048, 0, 0, 0, 0, 1.f);

  // everything else: one fused row-local kernel
  brain<<<256, 512, 0, stream>>>(lat, win, wout, wah, woh,
                                 b_in, b_out, b_ah, b_oh,
                                 W_ap, b_ap, W_av, b_av,
                                 W_op, b_op, W_ov, b_ov, out);
}

// Round 7
// 363.011 us; speedup vs baseline: 1.1974x; 1.1974x over previous
//
#include <hip/hip_runtime.h>

typedef unsigned short u16;
typedef __bf16 bf16x8 __attribute__((ext_vector_type(8)));
typedef float f32x4 __attribute__((ext_vector_type(4)));

// ---------- sizes ----------
#define Bsz 8192
#define Fdim 1024
#define Udim 512
#define Odim 3
#define Adim 6
#define Hdim 4

// ws element offsets (u16 elements)
#define OFF_FEAT   0
#define OFF_WAL    8388608     // W_lat = [W_al ; W_ol] contiguous (2048 x 1024)
#define OFF_WIN    10485760
#define OFF_WOUT   11272192
#define OFF_WAH    11534336
#define OFF_WOH    12058624
#define OFF_LAT    12845056    // B x 2048 : [agent_latent | opp0 | opp1 | opp2]
#define OFF_Q      29622272    // B x 512
#define OFF_KV     33816576    // 3 x B x 1024 : [k | v]
#define OFF_ATT    58982400    // B x 512
#define OFF_AGH    63176704    // B x 512
#define OFF_OPH    67371008    // 3 x B x 512
#define OFF_WOUTT  79953920    // 512 x 512 bf16 : W_out^T
#define OFF_WCOMB  80216064    // 512 x 512 bf16 : W_ah[:,512:] @ W_out
#define OFF_BAHC   80478208    // 512 f32 : b_ah + W_ah[:,512:] @ b_out
#define OFF_ZB     80479232    // 512 f32 : zeros

// d_out offsets (fp32 elements)
#define OUT_AP 0
#define OUT_AV 49152
#define OUT_OP 57344
#define OUT_OV 204800
#define OUT_IN 229376

__device__ __forceinline__ u16 f2bf(float f) {
  return __builtin_bit_cast(u16, (__bf16)f);
}
__device__ __forceinline__ float bf2f(u16 u) {
  return (float)__builtin_bit_cast(__bf16, u);
}

__device__ __forceinline__ void gload16(const u16* g, u16* s) {
  __builtin_amdgcn_global_load_lds(
      (const __attribute__((address_space(1))) unsigned int*)g,
      (__attribute__((address_space(3))) unsigned int*)s, 16, 0, 0);
}

// ---------- fp32 -> bf16 conversion of features + all GEMM weights ----------
#define CV_E0 2097152
#define CV_E1 2228224
#define CV_E2 2621440
#define CV_E3 2818048
#define CV_E4 2883584
#define CV_E5 3014656
#define CV_E6 3211264
__global__ __launch_bounds__(256) void convert_all(
    const float* __restrict__ f, const float* __restrict__ wal,
    const float* __restrict__ wol, const float* __restrict__ win,
    const float* __restrict__ wout, const float* __restrict__ wah,
    const float* __restrict__ woh, u16* __restrict__ dst) {
  int i = blockIdx.x * 256 + threadIdx.x;
  if (i >= CV_E6) return;
  const float* src;
  int base;
  if (i < CV_E0)      { src = f;    base = 0; }
  else if (i < CV_E1) { src = wal;  base = CV_E0; }
  else if (i < CV_E2) { src = wol;  base = CV_E1; }
  else if (i < CV_E3) { src = win;  base = CV_E2; }
  else if (i < CV_E4) { src = wout; base = CV_E3; }
  else if (i < CV_E5) { src = wah;  base = CV_E4; }
  else                { src = woh;  base = CV_E5; }
  float4 v = ((const float4*)src)[i - base];
  ushort4 o;
  o.x = f2bf(v.x); o.y = f2bf(v.y); o.z = f2bf(v.z); o.w = f2bf(v.w);
  ((ushort4*)dst)[i] = o;
}

// ---------- prep: W_out^T (bf16, LDS tile transpose) + b_comb + zeros ----------
// blocks 0..63: 64x64 transpose tiles. block 64: bahc = b_ah + WahR@b_out, zb=0.
__global__ __launch_bounds__(256) void prep(
    const float* __restrict__ wout_f, const float* __restrict__ wah_f,
    const float* __restrict__ bout_f, const float* __restrict__ bah_f,
    u16* __restrict__ woutT, float* __restrict__ bahc, float* __restrict__ zb) {
  if (blockIdx.x == 64) {
    int t = threadIdx.x;
    zb[t] = 0.f; zb[t + 256] = 0.f;
    for (int j = t; j < 512; j += 256) {
      float s = 0.f;
      for (int v = 0; v < 512; ++v)
        s += wah_f[j * 1024 + 512 + v] * bout_f[v];
      bahc[j] = bah_f[j] + s;
    }
    return;
  }
  __shared__ float tile[64][65];
  const int bx = blockIdx.x & 7, byy = blockIdx.x >> 3;
  const int v0 = byy * 64, u0 = bx * 64;
#pragma unroll
  for (int it = 0; it < 16; ++it) {
    int idx = it * 256 + threadIdx.x;
    int r = idx >> 6, c = idx & 63;
    tile[r][c] = wout_f[(v0 + r) * 512 + u0 + c];
  }
  __syncthreads();
#pragma unroll
  for (int it = 0; it < 16; ++it) {
    int idx = it * 256 + threadIdx.x;
    int r = idx >> 6, c = idx & 63;
    woutT[(u0 + r) * 512 + v0 + c] = f2bf(tile[c][r]);  // woutT[u][v]=W_out[v][u]
  }
}

// ============================================================================
// 256x256 8-phase bf16 GEMM for lat = elu(feat @ W_lat^T + b). Unchanged from
// round 2 (verified: FETCH near-ideal, 0 bank conflicts).
// ============================================================================
#define BAR() __builtin_amdgcn_s_barrier()
#define FENCE() asm volatile("" ::: "memory")
#define LGKM0() asm volatile("s_waitcnt lgkmcnt(0)" ::: "memory")
#define VMW(n) asm volatile("s_waitcnt vmcnt(" #n ")" ::: "memory")
#define MFMA(a, b, c) __builtin_amdgcn_mfma_f32_16x16x32_bf16(a, b, c, 0, 0, 0)
#define STAGE(MAT, SRC, LD, buf, ks, kb) do {                    \
    const u16* _s = (SRC) + (size_t)(kb) + (ks) * 32;            \
    gload16(_s, &MAT[buf][ks][wave * 512]);                      \
    gload16(_s + (size_t)128 * (LD), &MAT[buf][ks][4096 + wave * 512]); \
  } while (0)
#define RD_A(cur, ks, mh) do {                                   \
    _Pragma("unroll")                                            \
    for (int mi = 0; mi < 4; mi++)                               \
      a0[mi] = *(const bf16x8*)&As[cur][ks][aoff + (mh)*2048 + mi*512]; \
  } while (0)
#define RD_B(cur, ks) do {                                       \
    _Pragma("unroll")                                            \
    for (int ni = 0; ni < 4; ni++)                               \
      b0[ni] = *(const bf16x8*)&Bs[cur][ks][boff + ni*512];      \
  } while (0)
#define MFMA8(mh) do {                                           \
    __builtin_amdgcn_s_setprio(1);                               \
    _Pragma("unroll")                                            \
    for (int mi = 0; mi < 4; mi++) {                             \
      _Pragma("unroll")                                          \
      for (int ni = 0; ni < 4; ni++)                             \
        acc[(mh)*4+mi][ni] = MFMA(a0[mi], b0[ni], acc[(mh)*4+mi][ni]); \
    }                                                            \
    __builtin_amdgcn_s_setprio(0);                               \
  } while (0)

template <bool ELU>
__global__ __launch_bounds__(512, 2) void gemm256(
    const u16* __restrict__ A, const u16* __restrict__ Bw, u16* __restrict__ C,
    const float* __restrict__ bias1, const float* __restrict__ bias2,
    int bsplit, int K, int lda, int ldb, int ldc,
    long sAz, long sBz, long sCz, int sbz, float scale) {
  __shared__ __align__(16) u16 As[2][2][8192];
  __shared__ __align__(16) u16 Bs[2][2][8192];
  const int tid = threadIdx.x;
  const int wave = tid >> 6, lane = tid & 63;
  const int wr = wave >> 2, wc = wave & 3;

  const int nx = gridDim.x, ny = gridDim.y;
  const int nxy = nx * ny;
  const int nwg = nxy * gridDim.z;
  const int orig = blockIdx.x + nx * (blockIdx.y + ny * blockIdx.z);
  const int xcd = orig & 7;
  const int qd = nwg >> 3, rd = nwg & 7;
  const int wg = (xcd < rd ? xcd * (qd + 1) : rd * (qd + 1) + (xcd - rd) * qd)
               + (orig >> 3);
  const int z = wg / nxy;
  const int rem = wg - z * nxy;
  const int by = rem / nx;
  const int bx = rem - by * nx;

  A += (size_t)z * sAz;
  Bw += (size_t)z * sBz;
  C += (size_t)z * sCz;
  bias1 += (size_t)z * sbz;

  const int tM = by * 256, tN = bx * 256;

  const int srow = tid >> 2;
  const int schunk = ((tid & 3) ^ ((tid >> 3) & 3)) * 8;
  const u16* Asrc = A + (size_t)(tM + srow) * lda + schunk;
  const u16* Bsrc = Bw + (size_t)(tN + srow) * ldb + schunk;

  const int laneLo = lane & 15;
  const int pc8 = (((lane >> 4) ^ ((lane >> 1) & 3))) * 8;
  const int aoff = (wr * 128 + laneLo) * 32 + pc8;
  const int boff = (wc * 64 + laneLo) * 32 + pc8;

  f32x4 acc[8][4];
#pragma unroll
  for (int mi = 0; mi < 8; mi++)
#pragma unroll
    for (int ni = 0; ni < 4; ni++) acc[mi][ni] = (f32x4){0.f, 0.f, 0.f, 0.f};

  const int NT = K >> 6;

  STAGE(As, Asrc, lda, 0, 0, 0);
  STAGE(Bs, Bsrc, ldb, 0, 0, 0);
  STAGE(As, Asrc, lda, 0, 1, 0);
  STAGE(Bs, Bsrc, ldb, 0, 1, 0);
  VMW(4);
  BAR();

  int cur = 0;
  int kb = 64;
  bf16x8 a0[4], b0[4];
  for (int t = 0; t < NT; ++t) {
    const int nxt = cur ^ 1;
    const bool st = (t + 1 < NT);
    RD_B(cur, 0);
    RD_A(cur, 0, 0);
    if (st) STAGE(As, Asrc, lda, nxt, 0, kb);
    FENCE(); BAR(); LGKM0();
    MFMA8(0);
    FENCE(); BAR();
    RD_A(cur, 0, 1);
    if (st) STAGE(Bs, Bsrc, ldb, nxt, 0, kb);
    FENCE(); BAR(); LGKM0();
    MFMA8(1);
    if (st) { VMW(4); } else { VMW(0); }
    BAR();
    RD_B(cur, 1);
    RD_A(cur, 1, 0);
    if (st) STAGE(As, Asrc, lda, nxt, 1, kb);
    FENCE(); BAR(); LGKM0();
    MFMA8(0);
    FENCE(); BAR();
    RD_A(cur, 1, 1);
    if (st) STAGE(Bs, Bsrc, ldb, nxt, 1, kb);
    FENCE(); BAR(); LGKM0();
    MFMA8(1);
    if (st) { VMW(4); BAR(); }
    cur = nxt;
    kb += 64;
  }

#pragma unroll
  for (int ni = 0; ni < 4; ni++) {
    const int col = tN + wc * 64 + ni * 16 + laneLo;
    const float bv = (col < bsplit) ? bias1[col] : bias2[col - bsplit];
#pragma unroll
    for (int gm = 0; gm < 8; gm++) {
      const int row0 = tM + wr * 128 + gm * 16 + (lane >> 4) * 4;
#pragma unroll
      for (int r = 0; r < 4; r++) {
        float v = (acc[gm][ni][r] + bv) * scale;
        if (ELU) v = v > 0.f ? v : (__expf(v) - 1.f);
        C[(size_t)(row0 + r) * ldc + col] = f2bf(v);
      }
    }
  }
}
#undef STAGE
#undef RD_A
#undef RD_B
#undef MFMA8

// ============================================================================
// gemm_bt: r1/r2-verified 128xBN tile, now with symmetric split-A AND split-B
// at the same ksplit (r2 verified split-A in the agh launch).
// C[m,n] = act((sum_k A[m,k]*Bw[n,k] + bias[n]) * scale)
// ============================================================================
template <int BN, bool ELU>
__global__ __launch_bounds__(256) void gemm_bt(
    const u16* __restrict__ A, const u16* __restrict__ A2,
    const u16* __restrict__ Bw, const u16* __restrict__ Bw2,
    int ksplit, int lda, int lda2, int ldb, int ldb2,
    u16* __restrict__ C, const float* __restrict__ bias,
    int K, int ldc, float scale) {
  constexpr int BM = 128, BK = 32;
  constexpr int NI = BN / 32;
  __shared__ __align__(16) u16 As[BM * BK];
  __shared__ __align__(16) u16 Bs[BN * BK];
  const int wave = threadIdx.x >> 6, lane = threadIdx.x & 63;

  // XCD swizzle (2D grid)
  const int nx = gridDim.x;
  const int nwg = nx * gridDim.y;
  const int orig = blockIdx.x + nx * blockIdx.y;
  const int xcd = orig & 7;
  const int qd = nwg >> 3, rd = nwg & 7;
  const int wg = (xcd < rd ? xcd * (qd + 1) : rd * (qd + 1) + (xcd - rd) * qd)
               + (orig >> 3);
  const int by = wg / nx, bx = wg - by * nx;
  const int tM = by * BM, tN = bx * BN;
  const int wr = wave >> 1, wc = wave & 1;

  f32x4 acc[4][NI];
#pragma unroll
  for (int i = 0; i < 4; i++)
#pragma unroll
    for (int j = 0; j < NI; j++) acc[i][j] = (f32x4){0.f, 0.f, 0.f, 0.f};

  const int srow = lane >> 2;
  const int scol = (lane & 3) * 8;

  for (int k0 = 0; k0 < K; k0 += BK) {
    const u16 *Ap, *Bp;
    int la, lb, kk;
    if (k0 < ksplit) { Ap = A;  la = lda;  Bp = Bw;  lb = ldb;  kk = k0; }
    else             { Ap = A2; la = lda2; Bp = Bw2; lb = ldb2; kk = k0 - ksplit; }
    __syncthreads();
#pragma unroll
    for (int i = 0; i < 2; ++i) {
      int r = wave * 32 + i * 16;
      gload16(Ap + (size_t)(tM + r + srow) * la + kk + scol, &As[r * BK]);
    }
#pragma unroll
    for (int i = 0; i < BN / 64; ++i) {
      int r = (wave * (BN / 64) + i) * 16;
      gload16(Bp + (size_t)(tN + r + srow) * lb + kk + scol, &Bs[r * BK]);
    }
    __syncthreads();
    bf16x8 af[4], bfr[NI];
#pragma unroll
    for (int mi = 0; mi < 4; mi++)
      af[mi] = *(const bf16x8*)&As[(wr * 64 + mi * 16 + (lane & 15)) * BK + (lane >> 4) * 8];
#pragma unroll
    for (int ni = 0; ni < NI; ni++)
      bfr[ni] = *(const bf16x8*)&Bs[(wc * (BN / 2) + ni * 16 + (lane & 15)) * BK + (lane >> 4) * 8];
#pragma unroll
    for (int mi = 0; mi < 4; mi++)
#pragma unroll
      for (int ni = 0; ni < NI; ni++)
        acc[mi][ni] = __builtin_amdgcn_mfma_f32_16x16x32_bf16(af[mi], bfr[ni], acc[mi][ni], 0, 0, 0);
  }

#pragma unroll
  for (int ni = 0; ni < NI; ni++) {
    int col = tN + wc * (BN / 2) + ni * 16 + (lane & 15);
    float bv = bias[col];
#pragma unroll
    for (int mi = 0; mi < 4; mi++) {
      int row0 = tM + wr * 64 + mi * 16 + (lane >> 4) * 4;
#pragma unroll
      for (int r = 0; r < 4; r++) {
        float v = (acc[mi][ni][r] + bv) * scale;
        if (ELU) v = v > 0.f ? v : (__expf(v) - 1.f);
        C[(size_t)(row0 + r) * ldc + col] = f2bf(v);
      }
    }
  }
}

// ============================================================================
// mega: one z-routed launch for all independent post-lat GEMMs.
//   z=0     : q    = (al @ Wq^T + bq) / sqrt(128)        (N=512)
//   z=1..3  : kv_o = opp_o @ [Wk;Wv]^T + [bk;bv]         (N=1024)
//   z=4..6  : oph_o= elu(opp_o @ Woh_o^T + b_oh_o)       (N=512)
//   z=7     : Wcomb= WahR @ WoutT (weight composition)    (M=512, N=512)
// Inner loop identical to r1-verified gemm_bt<128>. Blocks outside a z's
// M/N range exit immediately.
// ============================================================================
__global__ __launch_bounds__(256) void mega(
    const u16* __restrict__ lat, const u16* __restrict__ win,
    const u16* __restrict__ woh, const u16* __restrict__ wahb,
    const u16* __restrict__ woutT,
    u16* __restrict__ qb, u16* __restrict__ kvb, u16* __restrict__ oph,
    u16* __restrict__ wcomb,
    const float* __restrict__ b_in, const float* __restrict__ b_oh,
    const float* __restrict__ zb) {
  constexpr int BM = 128, BK = 32, BN = 128, NI = 4;
  __shared__ __align__(16) u16 As[BM * BK];
  __shared__ __align__(16) u16 Bs[BN * BK];
  const int wave = threadIdx.x >> 6, lane = threadIdx.x & 63;

  // XCD swizzle over the whole 8x64x8 grid
  const int nx = gridDim.x, ny = gridDim.y;
  const int nxy = nx * ny;
  const int nwg = nxy * gridDim.z;
  const int orig = blockIdx.x + nx * (blockIdx.y + ny * blockIdx.z);
  const int xcd = orig & 7;
  const int qd = nwg >> 3, rd = nwg & 7;
  const int wg = (xcd < rd ? xcd * (qd + 1) : rd * (qd + 1) + (xcd - rd) * qd)
               + (orig >> 3);
  const int z = wg / nxy;
  const int rem = wg - z * nxy;
  const int by = rem / nx;
  const int bx = rem - by * nx;

  // routing
  const u16 *A, *Bw;
  u16* C;
  const float* bias;
  int N, ldc, M = 8192, lda = 2048;
  bool elu = false;
  float scale = 1.f;
  if (z == 0) {
    A = lat; Bw = win; C = qb; bias = b_in;
    N = 512; ldc = 512; scale = 0.08838834764831845f;
  } else if (z <= 3) {
    A = lat + 512 * z; Bw = win + 262144;
    C = kvb + (size_t)(z - 1) * 8388608; bias = b_in + 512;
    N = 1024; ldc = 1024;
  } else if (z <= 6) {
    A = lat + 512 * (z - 3); Bw = woh + (size_t)(z - 4) * 262144;
    C = oph + (size_t)(z - 4) * 4194304; bias = b_oh + (z - 4) * 512;
    N = 512; ldc = 512; elu = true;
  } else {
    A = wahb + 512; lda = 1024; Bw = woutT;
    C = wcomb; bias = zb;
    N = 512; ldc = 512; M = 512;
  }
  const int tM = by * BM, tN = bx * BN;
  if (tN >= N || tM >= M) return;
  const int wr = wave >> 1, wc = wave & 1;

  f32x4 acc[4][NI];
#pragma unroll
  for (int i = 0; i < 4; i++)
#pragma unroll
    for (int j = 0; j < NI; j++) acc[i][j] = (f32x4){0.f, 0.f, 0.f, 0.f};

  const int srow = lane >> 2;
  const int scol = (lane & 3) * 8;

  for (int k0 = 0; k0 < 512; k0 += BK) {
    __syncthreads();
#pragma unroll
    for (int i = 0; i < 2; ++i) {
      int r = wave * 32 + i * 16;
      gload16(A + (size_t)(tM + r + srow) * lda + k0 + scol, &As[r * BK]);
    }
#pragma unroll
    for (int i = 0; i < 2; ++i) {
      int r = (wave * 2 + i) * 16;
      gload16(Bw + (size_t)(tN + r + srow) * 512 + k0 + scol, &Bs[r * BK]);
    }
    __syncthreads();
    bf16x8 af[4], bfr[NI];
#pragma unroll
    for (int mi = 0; mi < 4; mi++)
      af[mi] = *(const bf16x8*)&As[(wr * 64 + mi * 16 + (lane & 15)) * BK + (lane >> 4) * 8];
#pragma unroll
    for (int ni = 0; ni < NI; ni++)
      bfr[ni] = *(const bf16x8*)&Bs[(wc * 64 + ni * 16 + (lane & 15)) * BK + (lane >> 4) * 8];
#pragma unroll
    for (int mi = 0; mi < 4; mi++)
#pragma unroll
      for (int ni = 0; ni < NI; ni++)
        acc[mi][ni] = __builtin_amdgcn_mfma_f32_16x16x32_bf16(af[mi], bfr[ni], acc[mi][ni], 0, 0, 0);
  }

#pragma unroll
  for (int ni = 0; ni < NI; ni++) {
    int col = tN + wc * 64 + ni * 16 + (lane & 15);
    float bv = bias[col];
#pragma unroll
    for (int mi = 0; mi < 4; mi++) {
      int row0 = tM + wr * 64 + mi * 16 + (lane >> 4) * 4;
#pragma unroll
      for (int r = 0; r < 4; r++) {
        float v = (acc[mi][ni][r] + bv) * scale;
        if (elu) v = v > 0.f ? v : (__expf(v) - 1.f);
        C[(size_t)(row0 + r) * ldc + col] = f2bf(v);
      }
    }
  }
}

// ---------- attention (r1-verified): scores/softmax over O=3, out + influ ----
__global__ __launch_bounds__(256) void attn_kernel(
    const u16* __restrict__ q, const u16* __restrict__ kv,
    u16* __restrict__ attn, float* __restrict__ influ) {
  const int wave = threadIdx.x >> 6, lane = threadIdx.x & 63;
  const int b = blockIdx.x * 4 + wave;
  const size_t qb = (size_t)b * 512;
  float wacc0 = 0.f, wacc1 = 0.f, wacc2 = 0.f;
#pragma unroll
  for (int h = 0; h < 4; ++h) {
    const int off = h * 128 + lane * 2;
    ushort2 qu = *(const ushort2*)(q + qb + off);
    float qx = bf2f(qu.x), qy = bf2f(qu.y);
    float s[3];
#pragma unroll
    for (int o = 0; o < 3; ++o) {
      ushort2 ku = *(const ushort2*)(kv + (size_t)o * (Bsz * 1024) + (size_t)b * 1024 + off);
      float p = qx * bf2f(ku.x) + qy * bf2f(ku.y);
#pragma unroll
      for (int d = 32; d; d >>= 1) p += __shfl_xor(p, d, 64);
      s[o] = p;
    }
    float m = fmaxf(s[0], fmaxf(s[1], s[2]));
    float e0 = __expf(s[0] - m), e1 = __expf(s[1] - m), e2 = __expf(s[2] - m);
    float inv = 1.f / (e0 + e1 + e2);
    float w0 = e0 * inv, w1 = e1 * inv, w2 = e2 * inv;
    wacc0 += w0; wacc1 += w1; wacc2 += w2;
    float ax = 0.f, ay = 0.f;
#pragma unroll
    for (int o = 0; o < 3; ++o) {
      float w = (o == 0) ? w0 : (o == 1) ? w1 : w2;
      ushort2 vu = *(const ushort2*)(kv + (size_t)o * (Bsz * 1024) + (size_t)b * 1024 + 512 + off);
      ax += w * bf2f(vu.x);
      ay += w * bf2f(vu.y);
    }
    ushort2 st; st.x = f2bf(ax); st.y = f2bf(ay);
    *(ushort2*)(attn + qb + off) = st;
  }
  if (lane == 0) {
    influ[b * 3 + 0] = wacc0 * 0.25f;
    influ[b * 3 + 1] = wacc1 * 0.25f;
    influ[b * 3 + 2] = wacc2 * 0.25f;
  }
}

// ---------- final heads (r0-verified): 28 length-512 dots per row ----------
__global__ __launch_bounds__(256) void heads_kernel(
    const u16* __restrict__ ah, const u16* __restrict__ oh,
    const float* __restrict__ Wap, const float* __restrict__ bap,
    const float* __restrict__ Wav, const float* __restrict__ bav,
    const float* __restrict__ Wop, const float* __restrict__ bop,
    const float* __restrict__ Wov, const float* __restrict__ bov,
    float* __restrict__ out) {
  __shared__ float sW[14336];
  for (int i = threadIdx.x; i < 14336; i += 256) {
    int s = i / 3584, rem = i - s * 3584;
    float v;
    if (s == 0) {
      v = (rem < 3072) ? Wap[rem] : Wav[rem - 3072];
    } else {
      int o = s - 1;
      v = (rem < 3072) ? Wop[o * 3072 + rem] : Wov[o * 512 + (rem - 3072)];
    }
    sW[i] = v;
  }
  __syncthreads();
  const int wave = threadIdx.x >> 6, lane = threadIdx.x & 63;
  const int kq = lane & 7, r = lane >> 3;
  const int b = blockIdx.x * 32 + wave * 8 + r;

  const u16* srcs[4] = {ah + (size_t)b * 512,
                        oh + (size_t)b * 512,
                        oh + (size_t)(Bsz + b) * 512,
                        oh + (size_t)(2 * Bsz + b) * 512};
  bf16x8 a[4][8];
#pragma unroll
  for (int s = 0; s < 4; s++)
#pragma unroll
    for (int c = 0; c < 8; c++)
      a[s][c] = *(const bf16x8*)(srcs[s] + c * 64 + kq * 8);

#pragma unroll
  for (int s = 0; s < 4; s++) {
#pragma unroll
    for (int p = 0; p < 7; p++) {
      const float* w = &sW[s * 3584 + p * 512 + kq * 8];
      float acc = 0.f;
#pragma unroll
      for (int c = 0; c < 8; c++) {
#pragma unroll
        for (int j = 0; j < 8; j++)
          acc += (float)a[s][c][j] * w[c * 64 + j];
      }
      acc += __shfl_xor(acc, 1, 64);
      acc += __shfl_xor(acc, 2, 64);
      acc += __shfl_xor(acc, 4, 64);
      if (kq == p) {
        if (s == 0) {
          if (p < 6) out[OUT_AP + b * 6 + p] = acc + bap[p];
          else       out[OUT_AV + b] = acc + bav[0];
        } else {
          int o = s - 1;
          if (p < 6) out[OUT_OP + b * 18 + o * 6 + p] = acc + bop[o * 6 + p];
          else       out[OUT_OV + b * 3 + o] = acc + bov[o];
        }
      }
    }
  }
}

extern "C" void kernel_launch(void* const* d_in, const int* in_sizes, int n_in,
                              void* d_out, int out_size, void* d_ws, size_t ws_size,
                              hipStream_t stream) {
  (void)in_sizes; (void)n_in; (void)out_size; (void)ws_size;
  const float* f     = (const float*)d_in[0];
  const float* W_al  = (const float*)d_in[1];
  const float* b_al  = (const float*)d_in[2];
  const float* W_in  = (const float*)d_in[3];
  const float* b_in  = (const float*)d_in[4];
  const float* W_out = (const float*)d_in[5];
  const float* b_out = (const float*)d_in[6];
  const float* W_ah  = (const float*)d_in[7];
  const float* b_ah  = (const float*)d_in[8];
  const float* W_ap  = (const float*)d_in[9];
  const float* b_ap  = (const float*)d_in[10];
  const float* W_av  = (const float*)d_in[11];
  const float* b_av  = (const float*)d_in[12];
  const float* W_ol  = (const float*)d_in[13];
  const float* b_ol  = (const float*)d_in[14];
  const float* W_oh  = (const float*)d_in[15];
  const float* b_oh  = (const float*)d_in[16];
  const float* W_op  = (const float*)d_in[17];
  const float* b_op  = (const float*)d_in[18];
  const float* W_ov  = (const float*)d_in[19];
  const float* b_ov  = (const float*)d_in[20];
  float* out = (float*)d_out;
  u16* ws = (u16*)d_ws;

  u16* feat  = ws + OFF_FEAT;
  u16* wal   = ws + OFF_WAL;    // [W_al ; W_ol] = W_lat (2048 x 1024)
  u16* win   = ws + OFF_WIN;
  u16* wahb  = ws + OFF_WAH;
  u16* woh   = ws + OFF_WOH;
  u16* lat   = ws + OFF_LAT;    // B x 2048
  u16* qb    = ws + OFF_Q;
  u16* kvb   = ws + OFF_KV;
  u16* att   = ws + OFF_ATT;
  u16* agh   = ws + OFF_AGH;
  u16* oph   = ws + OFF_OPH;
  u16* woutT = ws + OFF_WOUTT;
  u16* wcomb = ws + OFF_WCOMB;
  float* bahc = (float*)(ws + OFF_BAHC);
  float* zb   = (float*)(ws + OFF_ZB);

  convert_all<<<12544, 256, 0, stream>>>(f, W_al, W_ol, W_in, W_out, W_ah,
                                         W_oh, ws);
  prep<<<65, 256, 0, stream>>>(W_out, W_ah, b_out, b_ah, woutT, bahc, zb);

  // lat = elu(feat @ W_lat^T + [b_al|b_ol]) : B x 2048
  gemm256<true><<<dim3(8, 32, 1), 512, 0, stream>>>(
      feat, wal, lat, b_al, b_ol, 512, 1024, 1024, 1024, 2048, 0, 0, 0, 0, 1.f);

  // q, kv(x3), opp_heads(x3), Wcomb : one z-routed launch
  mega<<<dim3(8, 64, 8), 256, 0, stream>>>(
      lat, win, woh, wahb, woutT, qb, kvb, oph, wcomb, b_in, b_oh, zb);

  attn_kernel<<<2048, 256, 0, stream>>>(qb, kvb, att, out + OUT_IN);

  // agent_head = elu([al | attn] @ [WahL ; Wcomb]^T + bahc)  (aout folded away)
  gemm_bt<64, true><<<dim3(8, 64), 256, 0, stream>>>(
      lat, att, wahb, wcomb, 512, 2048, 512, 1024, 512,
      agh, bahc, 1024, 512, 1.f);

  heads_kernel<<<256, 256, 0, stream>>>(agh, oph, W_ap, b_ap, W_av, b_av,
                                        W_op, b_op, W_ov, b_ov, out);
}